// Round 8
// baseline (483.087 us; speedup 1.0000x reference)
//
#include <hip/hip_runtime.h>
#include <hip/hip_bf16.h>
#include <stdint.h>

// GraphConv x2 — round 8: round-7 design with the nontemporal-store compile fix
// (pack float2 pair as uint64_t for the builtin; identical byte layout).
//   CSR by dst (proven). Pipeline:
//     gemm1:         xr1 = x @ Wrel1^T (bf16);  d_out = x @ Wroot1^T + b1 (f32)
//     gather1_fused: h = relu(sum_j w_j*xr1[src_j] + d_out[i])  [registers]
//                    xr2[i] = h @ Wrel2^T (bf16);  d_out[i] = h @ Wroot2^T + b2
//     gather2:       d_out[i] += sum_j w_j*xr2[src_j]
// N=100000, E=1600000, D=64

#define D 64
#define SCAN_CHUNK 1024

typedef unsigned int   u32;
typedef unsigned short u16;

__device__ __forceinline__ float bf2f(u16 v) {
    return __uint_as_float(((u32)v) << 16);
}
__device__ __forceinline__ u16 f2bf(float f) {
    u32 u = __float_as_uint(f);
    u32 r = (u + 0x7fffu + ((u >> 16) & 1u)) >> 16;   // round-to-nearest-even
    return (u16)r;
}

// ---------------- CSR build (proven; nt store on pairs via u64 pack) ----------------
__global__ __launch_bounds__(256) void hist_kernel(
    const int* __restrict__ ei, int* __restrict__ deg, int E_)
{
    int e = blockIdx.x * 256 + threadIdx.x;
    if (e >= E_) return;
    atomicAdd(&deg[ei[E_ + e]], 1);
}

__global__ __launch_bounds__(256) void scan1_kernel(
    const int* __restrict__ deg, int* __restrict__ loc, int* __restrict__ partial, int n)
{
    __shared__ int wsum[4];
    int t = threadIdx.x;
    int base = blockIdx.x * SCAN_CHUNK + t * 4;
    int v0 = (base + 0 < n) ? deg[base + 0] : 0;
    int v1 = (base + 1 < n) ? deg[base + 1] : 0;
    int v2 = (base + 2 < n) ? deg[base + 2] : 0;
    int v3 = (base + 3 < n) ? deg[base + 3] : 0;
    int s = v0 + v1 + v2 + v3;
    int lane = t & 63, wave = t >> 6;
    int inc = s;
    for (int off = 1; off < 64; off <<= 1) {
        int u = __shfl_up(inc, off);
        if (lane >= off) inc += u;
    }
    if (lane == 63) wsum[wave] = inc;
    __syncthreads();
    int woff = 0;
    for (int w = 0; w < wave; ++w) woff += wsum[w];
    int ex = woff + inc - s;
    if (base + 0 < n) loc[base + 0] = ex;
    if (base + 1 < n) loc[base + 1] = ex + v0;
    if (base + 2 < n) loc[base + 2] = ex + v0 + v1;
    if (base + 3 < n) loc[base + 3] = ex + v0 + v1 + v2;
    if (t == 255) partial[blockIdx.x] = woff + inc;
}

__global__ __launch_bounds__(1024) void scan2_kernel(int* __restrict__ partial, int nchunk)
{
    __shared__ int sd[1024];
    int t = threadIdx.x;
    if (t < nchunk) sd[t] = partial[t];
    __syncthreads();
    if (t == 0) {
        int run = 0;
        for (int i = 0; i < nchunk; ++i) { int v = sd[i]; sd[i] = run; run += v; }
    }
    __syncthreads();
    if (t < nchunk) partial[t] = sd[t];
}

__global__ __launch_bounds__(256) void scan3_kernel(
    int* __restrict__ rowptr, const int* __restrict__ partial,
    int* __restrict__ cursor, int n, int Etot)
{
    int i = blockIdx.x * 256 + threadIdx.x;
    if (i == 0) rowptr[n] = Etot;
    if (i >= n) return;
    int v = rowptr[i] + partial[i >> 10];
    rowptr[i] = v;
    cursor[i] = v;
}

__global__ __launch_bounds__(256) void fill_kernel(
    const int* __restrict__ ei, const float* __restrict__ ew,
    int* __restrict__ cursor, uint64_t* __restrict__ pairs, int E_)
{
    int e = blockIdx.x * 256 + threadIdx.x;
    if (e >= E_) return;
    int src = ei[e];
    int dst = ei[E_ + e];
    int p = atomicAdd(&cursor[dst], 1);
    // low word = src, high word = weight bits (== float2{src_as_float, w} layout)
    uint64_t packed = (uint64_t)(u32)src | ((uint64_t)__float_as_uint(ew[e]) << 32);
    __builtin_nontemporal_store(packed, &pairs[p]);
}

// ---------------- gemm1: xr1 = x@Wrel1^T (bf16); io = x@Wroot1^T + b1 (f32) ----------------
#define GW 8   // waves/block (512 threads)
#define GR 4   // rows/wave
__global__ __launch_bounds__(512) void gemm_kernel(
    const float* __restrict__ xin,
    const float* __restrict__ Wrel, const float* __restrict__ brel,
    const float* __restrict__ Wroot,
    u16* __restrict__ xr, float* __restrict__ io, int Nn)
{
    __shared__ float WrelT[D][D + 1];   // WrelT[k][d] = Wrel[d*64+k]; pad kills conflicts
    __shared__ float WrootT[D][D + 1];
    __shared__ float bias[D];
    __shared__ float rowX[GW][GR][D];

    int tid = threadIdx.x;
    for (int i = tid; i < D * D; i += 512) {
        int d = i >> 6, k = i & 63;
        WrelT [k][d] = Wrel [i];
        WrootT[k][d] = Wroot[i];
    }
    if (tid < D) bias[tid] = brel[tid];
    __syncthreads();

    int wave = tid >> 6, lane = tid & 63;

    int base = (blockIdx.x * GW + wave) * GR;
    if (base >= Nn) return;             // wave-uniform, after barrier
    int nr = min(GR, Nn - base);

    for (int r = 0; r < nr; ++r)
        rowX[wave][r][lane] = xin[(size_t)(base + r) * D + lane];
    // same-wave LDS write->read (proven rounds 2/5/6)

    float aR[GR] = {0.f, 0.f, 0.f, 0.f};
    float aC[GR] = {0.f, 0.f, 0.f, 0.f};
#pragma unroll
    for (int k4 = 0; k4 < 16; ++k4) {
        float4 xv[GR];
#pragma unroll
        for (int r = 0; r < GR; ++r)
            xv[r] = *reinterpret_cast<const float4*>(&rowX[wave][r][k4 * 4]); // broadcast b128
#pragma unroll
        for (int kk = 0; kk < 4; ++kk) {
            float wr = WrelT [k4 * 4 + kk][lane];
            float wc = WrootT[k4 * 4 + kk][lane];
#pragma unroll
            for (int r = 0; r < GR; ++r) {
                float xk = (kk == 0) ? xv[r].x : (kk == 1) ? xv[r].y
                         : (kk == 2) ? xv[r].z : xv[r].w;
                aR[r] = fmaf(xk, wr, aR[r]);
                aC[r] = fmaf(xk, wc, aC[r]);
            }
        }
    }
    for (int r = 0; r < nr; ++r) {
        size_t o = (size_t)(base + r) * D + lane;
        xr[o] = f2bf(aR[r]);
        io[o] = aC[r] + bias[lane];
    }
}

// ---------------- gather1_fused ----------------
// per row i (one wave): acc = sum_j w_j*xr1[src_j] (u16 loads, round-5 control flow);
// h = relu(acc + io[i]); stage h in LDS; xr2[i]=h@Wrel2^T (bf16); io[i]=h@Wroot2^T+b2.
__global__ __launch_bounds__(512) void gather1_fused(
    const u16* __restrict__ xr1, const float2* __restrict__ pairs,
    const int* __restrict__ rowptr,
    const float* __restrict__ Wrel, const float* __restrict__ brel,
    const float* __restrict__ Wroot,
    u16* __restrict__ xr2, float* __restrict__ io, int Nn)
{
    __shared__ float WrelT[D][D + 1];
    __shared__ float WrootT[D][D + 1];
    __shared__ float bias[D];
    __shared__ float rowH[GW][D];

    int tid = threadIdx.x;
    for (int i = tid; i < D * D; i += 512) {
        int d = i >> 6, k = i & 63;
        WrelT [k][d] = Wrel [i];
        WrootT[k][d] = Wroot[i];
    }
    if (tid < D) bias[tid] = brel[tid];
    __syncthreads();

    int wave = tid >> 6, lane = tid & 63;

    for (int i = blockIdx.x * GW + wave; i < Nn; i += gridDim.x * GW) {
        int beg = rowptr[i], end = rowptr[i + 1];
        float acc = 0.f;
        for (int b = beg; b < end; b += 64) {
            int cnt = min(64, end - b);
            float2 pr = (lane < cnt) ? pairs[b + lane] : make_float2(0.f, 0.f);
            int ps = __float_as_int(pr.x);
            int j = 0;
            for (; j + 4 <= cnt; j += 4) {         // 4 independent gathers in flight
                int   s0 = __shfl(ps, j),     s1 = __shfl(ps, j + 1);
                int   s2 = __shfl(ps, j + 2), s3 = __shfl(ps, j + 3);
                float w0 = __shfl(pr.y, j),     w1 = __shfl(pr.y, j + 1);
                float w2 = __shfl(pr.y, j + 2), w3 = __shfl(pr.y, j + 3);
                float v0 = bf2f(xr1[(size_t)s0 * D + lane]);
                float v1 = bf2f(xr1[(size_t)s1 * D + lane]);
                float v2 = bf2f(xr1[(size_t)s2 * D + lane]);
                float v3 = bf2f(xr1[(size_t)s3 * D + lane]);
                acc += v0 * w0; acc += v1 * w1; acc += v2 * w2; acc += v3 * w3;
            }
            for (; j < cnt; ++j) {
                int s = __shfl(ps, j);
                float w = __shfl(pr.y, j);
                acc += bf2f(xr1[(size_t)s * D + lane]) * w;
            }
        }
        size_t o = (size_t)i * D + lane;
        float h = fmaxf(acc + io[o], 0.f);         // ReLU

        rowH[wave][lane] = h;
        // same-wave LDS write->read (proven)

        const float4* rH4 = reinterpret_cast<const float4*>(rowH[wave]);
        float aR = 0.f;
        float aC = bias[lane];
#pragma unroll
        for (int k4 = 0; k4 < 16; ++k4) {
            float4 hv = rH4[k4];                   // broadcast b128
            int k = k4 * 4;
            aR = fmaf(hv.x, WrelT [k + 0][lane], aR);
            aR = fmaf(hv.y, WrelT [k + 1][lane], aR);
            aR = fmaf(hv.z, WrelT [k + 2][lane], aR);
            aR = fmaf(hv.w, WrelT [k + 3][lane], aR);
            aC = fmaf(hv.x, WrootT[k + 0][lane], aC);
            aC = fmaf(hv.y, WrootT[k + 1][lane], aC);
            aC = fmaf(hv.z, WrootT[k + 2][lane], aC);
            aC = fmaf(hv.w, WrootT[k + 3][lane], aC);
        }
        xr2[o] = f2bf(aR);
        io[o]  = aC;        // row i fully owned by this wave: read io -> write io OK
    }
}

// ---------------- gather2: io[i] += sum_j w_j*xr2[src_j] (proven control flow, u16) ----------------
#define AW 8
__global__ __launch_bounds__(512) void gather2_kernel(
    const u16* __restrict__ xr, const float2* __restrict__ pairs,
    const int* __restrict__ rowptr, float* __restrict__ io, int Nn)
{
    int tid  = threadIdx.x;
    int wave = tid >> 6, lane = tid & 63;
    int i = blockIdx.x * AW + wave;
    if (i >= Nn) return;                       // wave-uniform

    int beg = rowptr[i], end = rowptr[i + 1];
    float acc = 0.f;
    for (int b = beg; b < end; b += 64) {
        int cnt = min(64, end - b);
        float2 pr = (lane < cnt) ? pairs[b + lane] : make_float2(0.f, 0.f);
        int ps = __float_as_int(pr.x);
        int j = 0;
        for (; j + 4 <= cnt; j += 4) {
            int   s0 = __shfl(ps, j),     s1 = __shfl(ps, j + 1);
            int   s2 = __shfl(ps, j + 2), s3 = __shfl(ps, j + 3);
            float w0 = __shfl(pr.y, j),     w1 = __shfl(pr.y, j + 1);
            float w2 = __shfl(pr.y, j + 2), w3 = __shfl(pr.y, j + 3);
            float v0 = bf2f(xr[(size_t)s0 * D + lane]);
            float v1 = bf2f(xr[(size_t)s1 * D + lane]);
            float v2 = bf2f(xr[(size_t)s2 * D + lane]);
            float v3 = bf2f(xr[(size_t)s3 * D + lane]);
            acc += v0 * w0; acc += v1 * w1; acc += v2 * w2; acc += v3 * w3;
        }
        for (; j < cnt; ++j) {
            int s = __shfl(ps, j);
            float w = __shfl(pr.y, j);
            acc += bf2f(xr[(size_t)s * D + lane]) * w;
        }
    }
    size_t o = (size_t)i * D + lane;
    io[o] = acc + io[o];
}

extern "C" void kernel_launch(void* const* d_in, const int* in_sizes, int n_in,
                              void* d_out, int out_size, void* d_ws, size_t ws_size,
                              hipStream_t stream)
{
    const float* x      = (const float*)d_in[0];
    const int*   ei     = (const int*)  d_in[1];
    const float* ew     = (const float*)d_in[2];
    const float* Wrel1  = (const float*)d_in[3];
    const float* brel1  = (const float*)d_in[4];
    const float* Wroot1 = (const float*)d_in[5];
    const float* Wrel2  = (const float*)d_in[6];
    const float* brel2  = (const float*)d_in[7];
    const float* Wroot2 = (const float*)d_in[8];
    float* out = (float*)d_out;

    const int E_ = in_sizes[2];          // 1600000
    const int Nn = in_sizes[0] / D;      // 100000

    // workspace layout — 39.2 MB total (proven footprint)
    char* w = (char*)d_ws;
    size_t off = 0;
    u16*  xr1    = (u16*)(w + off); off += (size_t)Nn * D * sizeof(u16);   // 12.8 MB
    u16*  xr2    = (u16*)(w + off); off += (size_t)Nn * D * sizeof(u16);   // 12.8 MB
    int*  rowptr = (int*)(w + off); off += (size_t)(Nn + 1) * sizeof(int);
    int*  cursor = (int*)(w + off); off += (size_t)Nn * sizeof(int);
    int*  partial= (int*)(w + off); off += 1024 * sizeof(int);
    off = (off + 15) & ~(size_t)15;
    uint64_t* pairs = (uint64_t*)(w + off);                                // 12.8 MB

    const int nchunk  = (Nn + SCAN_CHUNK - 1) / SCAN_CHUNK;
    const int eBlocks = (E_ + 255) / 256;
    const int gemmBlocks   = (Nn + GW * GR - 1) / (GW * GR);
    const int g1Blocks     = 2048;                    // grid-stride, ~6 rows/wave
    const int g2Blocks     = (Nn + AW - 1) / AW;

    // ---- CSR build (reused by both layers) ----
    hipMemsetAsync(cursor, 0, (size_t)Nn * sizeof(int), stream);
    hist_kernel<<<eBlocks, 256, 0, stream>>>(ei, cursor, E_);
    scan1_kernel<<<nchunk, 256, 0, stream>>>(cursor, rowptr, partial, Nn);
    scan2_kernel<<<1, 1024, 0, stream>>>(partial, nchunk);
    scan3_kernel<<<(Nn + 255) / 256, 256, 0, stream>>>(rowptr, partial, cursor, Nn, E_);
    fill_kernel<<<eBlocks, 256, 0, stream>>>(ei, ew, cursor, pairs, E_);

    // ---- layer 1 pre-transform ----
    gemm_kernel<<<gemmBlocks, 512, 0, stream>>>(x, Wrel1, brel1, Wroot1, xr1, out, Nn);
    // ---- gather1 + relu + layer-2 pre-transform (fused) ----
    gather1_fused<<<g1Blocks, 512, 0, stream>>>(xr1, (const float2*)pairs, rowptr,
                                                Wrel2, brel2, Wroot2, xr2, out, Nn);
    // ---- gather2 (final) ----
    gather2_kernel<<<g2Blocks, 512, 0, stream>>>(xr2, (const float2*)pairs, rowptr, out, Nn);
}

// Round 9
// 418.861 us; speedup vs baseline: 1.1533x; 1.1533x over previous
//
#include <hip/hip_runtime.h>
#include <hip/hip_bf16.h>
#include <stdint.h>

// GraphConv x2 — round 9: round-6 proven structure + ILP-8 gather.
//   CSR by dst (proven). Per layer:
//     gemm:   xr = x @ Wrel^T ;  io = x @ Wroot^T + b     (io==d_out, f32)
//     gather: io[i] = [relu]( sum_j w_j * xr[src_j] + io[i] )  in place
//   Gather: identical lane mapping to round-5/6 (1 edge per wave-load,
//   xr[s*64+lane]), but 8 loads in flight + zero-weight padding (no tail).
// N=100000, E=1600000, D=64

#define D 64
#define SCAN_CHUNK 1024

typedef unsigned int u32;

// ---------------- CSR build (proven; nt u64 store in fill) ----------------
__global__ __launch_bounds__(256) void hist_kernel(
    const int* __restrict__ ei, int* __restrict__ deg, int E_)
{
    int e = blockIdx.x * 256 + threadIdx.x;
    if (e >= E_) return;
    atomicAdd(&deg[ei[E_ + e]], 1);
}

__global__ __launch_bounds__(256) void scan1_kernel(
    const int* __restrict__ deg, int* __restrict__ loc, int* __restrict__ partial, int n)
{
    __shared__ int wsum[4];
    int t = threadIdx.x;
    int base = blockIdx.x * SCAN_CHUNK + t * 4;
    int v0 = (base + 0 < n) ? deg[base + 0] : 0;
    int v1 = (base + 1 < n) ? deg[base + 1] : 0;
    int v2 = (base + 2 < n) ? deg[base + 2] : 0;
    int v3 = (base + 3 < n) ? deg[base + 3] : 0;
    int s = v0 + v1 + v2 + v3;
    int lane = t & 63, wave = t >> 6;
    int inc = s;
    for (int off = 1; off < 64; off <<= 1) {
        int u = __shfl_up(inc, off);
        if (lane >= off) inc += u;
    }
    if (lane == 63) wsum[wave] = inc;
    __syncthreads();
    int woff = 0;
    for (int w = 0; w < wave; ++w) woff += wsum[w];
    int ex = woff + inc - s;
    if (base + 0 < n) loc[base + 0] = ex;
    if (base + 1 < n) loc[base + 1] = ex + v0;
    if (base + 2 < n) loc[base + 2] = ex + v0 + v1;
    if (base + 3 < n) loc[base + 3] = ex + v0 + v1 + v2;
    if (t == 255) partial[blockIdx.x] = woff + inc;
}

__global__ __launch_bounds__(1024) void scan2_kernel(int* __restrict__ partial, int nchunk)
{
    __shared__ int sd[1024];
    int t = threadIdx.x;
    if (t < nchunk) sd[t] = partial[t];
    __syncthreads();
    if (t == 0) {
        int run = 0;
        for (int i = 0; i < nchunk; ++i) { int v = sd[i]; sd[i] = run; run += v; }
    }
    __syncthreads();
    if (t < nchunk) partial[t] = sd[t];
}

__global__ __launch_bounds__(256) void scan3_kernel(
    int* __restrict__ rowptr, const int* __restrict__ partial,
    int* __restrict__ cursor, int n, int Etot)
{
    int i = blockIdx.x * 256 + threadIdx.x;
    if (i == 0) rowptr[n] = Etot;
    if (i >= n) return;
    int v = rowptr[i] + partial[i >> 10];
    rowptr[i] = v;
    cursor[i] = v;
}

__global__ __launch_bounds__(256) void fill_kernel(
    const int* __restrict__ ei, const float* __restrict__ ew,
    int* __restrict__ cursor, uint64_t* __restrict__ pairs, int E_)
{
    int e = blockIdx.x * 256 + threadIdx.x;
    if (e >= E_) return;
    int src = ei[e];
    int dst = ei[E_ + e];
    int p = atomicAdd(&cursor[dst], 1);
    // low word = src, high word = weight bits (== float2{src_as_float, w} layout)
    uint64_t packed = (uint64_t)(u32)src | ((uint64_t)__float_as_uint(ew[e]) << 32);
    __builtin_nontemporal_store(packed, &pairs[p]);
}

// ---------------- pre-transform GEMM (round-6 verbatim, proven) ----------------
// xr[i] = xin[i] @ Wrel^T ;  io[i] = xin[i] @ Wroot^T + b.
// xin MAY ALIAS io (layer 2) — each row read before same-row write, same wave.
#define GW 8   // waves/block (512 threads)
#define GR 4   // rows/wave
__global__ __launch_bounds__(512) void gemm_kernel(
    const float* xin,
    const float* __restrict__ Wrel, const float* __restrict__ brel,
    const float* __restrict__ Wroot,
    float* __restrict__ xr, float* io, int Nn)
{
    __shared__ float WrelT[D][D + 1];   // WrelT[k][d] = Wrel[d*64+k]; pad kills conflicts
    __shared__ float WrootT[D][D + 1];
    __shared__ float bias[D];
    __shared__ float rowX[GW][GR][D];

    int tid = threadIdx.x;
    for (int i = tid; i < D * D; i += 512) {
        int d = i >> 6, k = i & 63;
        WrelT [k][d] = Wrel [i];
        WrootT[k][d] = Wroot[i];
    }
    if (tid < D) bias[tid] = brel[tid];
    __syncthreads();

    int wave = tid >> 6, lane = tid & 63;

    int base = (blockIdx.x * GW + wave) * GR;
    if (base >= Nn) return;             // wave-uniform, after barrier
    int nr = min(GR, Nn - base);

    for (int r = 0; r < nr; ++r)
        rowX[wave][r][lane] = xin[(size_t)(base + r) * D + lane];
    // same-wave LDS write->read (proven rounds 2/5/6)

    float aR[GR] = {0.f, 0.f, 0.f, 0.f};
    float aC[GR] = {0.f, 0.f, 0.f, 0.f};
#pragma unroll
    for (int k4 = 0; k4 < 16; ++k4) {
        float4 xv[GR];
#pragma unroll
        for (int r = 0; r < GR; ++r)
            xv[r] = *reinterpret_cast<const float4*>(&rowX[wave][r][k4 * 4]); // broadcast b128
#pragma unroll
        for (int kk = 0; kk < 4; ++kk) {
            float wr = WrelT [k4 * 4 + kk][lane];
            float wc = WrootT[k4 * 4 + kk][lane];
#pragma unroll
            for (int r = 0; r < GR; ++r) {
                float xk = (kk == 0) ? xv[r].x : (kk == 1) ? xv[r].y
                         : (kk == 2) ? xv[r].z : xv[r].w;
                aR[r] = fmaf(xk, wr, aR[r]);
                aC[r] = fmaf(xk, wc, aC[r]);
            }
        }
    }
    for (int r = 0; r < nr; ++r) {
        size_t o = (size_t)(base + r) * D + lane;
        xr[o] = aR[r];
        io[o] = aC[r] + bias[lane];
    }
}

// ---------------- gather: ILP-8, zero-weight padded (no serial tail) ----------------
#define AW 8
template <bool RELU>
__global__ __launch_bounds__(512) void gather_kernel(
    const float* __restrict__ xr, const float2* __restrict__ pairs,
    const int* __restrict__ rowptr, float* __restrict__ io, int Nn)
{
    int tid  = threadIdx.x;
    int wave = tid >> 6, lane = tid & 63;
    int i = blockIdx.x * AW + wave;
    if (i >= Nn) return;                       // wave-uniform

    int beg = rowptr[i], end = rowptr[i + 1];
    float acc = 0.f;
    for (int b = beg; b < end; b += 64) {
        int cnt = min(64, end - b);
        // lanes >= cnt carry (src=0, w=0): padded edges read row 0, add 0
        float2 pr = (lane < cnt) ? pairs[b + lane] : make_float2(0.f, 0.f);
        int ps = __float_as_int(pr.x);
        for (int j = 0; j < cnt; j += 8) {     // 8 independent gathers in flight
            int   s0 = __shfl(ps, j + 0), s1 = __shfl(ps, j + 1);
            int   s2 = __shfl(ps, j + 2), s3 = __shfl(ps, j + 3);
            int   s4 = __shfl(ps, j + 4), s5 = __shfl(ps, j + 5);
            int   s6 = __shfl(ps, j + 6), s7 = __shfl(ps, j + 7);
            float w0 = __shfl(pr.y, j + 0), w1 = __shfl(pr.y, j + 1);
            float w2 = __shfl(pr.y, j + 2), w3 = __shfl(pr.y, j + 3);
            float w4 = __shfl(pr.y, j + 4), w5 = __shfl(pr.y, j + 5);
            float w6 = __shfl(pr.y, j + 6), w7 = __shfl(pr.y, j + 7);
            float v0 = xr[(size_t)s0 * D + lane];
            float v1 = xr[(size_t)s1 * D + lane];
            float v2 = xr[(size_t)s2 * D + lane];
            float v3 = xr[(size_t)s3 * D + lane];
            float v4 = xr[(size_t)s4 * D + lane];
            float v5 = xr[(size_t)s5 * D + lane];
            float v6 = xr[(size_t)s6 * D + lane];
            float v7 = xr[(size_t)s7 * D + lane];
            acc = fmaf(v0, w0, acc); acc = fmaf(v1, w1, acc);
            acc = fmaf(v2, w2, acc); acc = fmaf(v3, w3, acc);
            acc = fmaf(v4, w4, acc); acc = fmaf(v5, w5, acc);
            acc = fmaf(v6, w6, acc); acc = fmaf(v7, w7, acc);
        }
    }
    size_t o = (size_t)i * D + lane;
    float v = acc + io[o];
    io[o] = RELU ? fmaxf(v, 0.f) : v;
}

extern "C" void kernel_launch(void* const* d_in, const int* in_sizes, int n_in,
                              void* d_out, int out_size, void* d_ws, size_t ws_size,
                              hipStream_t stream)
{
    const float* x      = (const float*)d_in[0];
    const int*   ei     = (const int*)  d_in[1];
    const float* ew     = (const float*)d_in[2];
    const float* Wrel1  = (const float*)d_in[3];
    const float* brel1  = (const float*)d_in[4];
    const float* Wroot1 = (const float*)d_in[5];
    const float* Wrel2  = (const float*)d_in[6];
    const float* brel2  = (const float*)d_in[7];
    const float* Wroot2 = (const float*)d_in[8];
    float* out = (float*)d_out;

    const int E_ = in_sizes[2];          // 1600000
    const int Nn = in_sizes[0] / D;      // 100000

    // workspace layout — 39.2 MB total (proven footprint)
    char* w = (char*)d_ws;
    size_t off = 0;
    float* xr     = (float*)(w + off); off += (size_t)Nn * D * sizeof(float); // 25.6 MB
    int*   rowptr = (int*)  (w + off); off += (size_t)(Nn + 1) * sizeof(int);
    int*   cursor = (int*)  (w + off); off += (size_t)Nn * sizeof(int);
    int*   partial= (int*)  (w + off); off += 1024 * sizeof(int);
    off = (off + 15) & ~(size_t)15;
    uint64_t* pairs = (uint64_t*)(w + off);                                   // 12.8 MB

    const int nchunk  = (Nn + SCAN_CHUNK - 1) / SCAN_CHUNK;
    const int eBlocks = (E_ + 255) / 256;
    const int gemmBlocks   = (Nn + GW * GR - 1) / (GW * GR);
    const int gatherBlocks = (Nn + AW - 1) / AW;

    // ---- CSR build (reused by both layers) ----
    hipMemsetAsync(cursor, 0, (size_t)Nn * sizeof(int), stream);
    hist_kernel<<<eBlocks, 256, 0, stream>>>(ei, cursor, E_);
    scan1_kernel<<<nchunk, 256, 0, stream>>>(cursor, rowptr, partial, Nn);
    scan2_kernel<<<1, 1024, 0, stream>>>(partial, nchunk);
    scan3_kernel<<<(Nn + 255) / 256, 256, 0, stream>>>(rowptr, partial, cursor, Nn, E_);
    fill_kernel<<<eBlocks, 256, 0, stream>>>(ei, ew, cursor, pairs, E_);

    // ---- layer 1: out = x@Wroot1^T+b1;  out = relu(gather(xr1) + out) ----
    gemm_kernel<<<gemmBlocks, 512, 0, stream>>>(x, Wrel1, brel1, Wroot1, xr, out, Nn);
    gather_kernel<true><<<gatherBlocks, 512, 0, stream>>>(xr, (const float2*)pairs, rowptr, out, Nn);

    // ---- layer 2: xr2 = h@Wrel2^T; out = h@Wroot2^T+b2 (in place);  out += gather(xr2) ----
    gemm_kernel<<<gemmBlocks, 512, 0, stream>>>(out, Wrel2, brel2, Wroot2, xr, out, Nn);
    gather_kernel<false><<<gatherBlocks, 512, 0, stream>>>(xr, (const float2*)pairs, rowptr, out, Nn);
}

// Round 10
// 363.025 us; speedup vs baseline: 1.3307x; 1.1538x over previous
//
#include <hip/hip_runtime.h>
#include <hip/hip_bf16.h>
#include <stdint.h>

// GraphConv x2 — round 10: round-9 passing base +
//   (1) bf16 xr (halve gather bytes), (2) system-scope write-through store
//   in fill (dodge L2 write-allocate thrash), (3) nt u64 loads of pairs.
//   CSR by dst (proven). Per layer:
//     gemm:   xr = x @ Wrel^T (bf16);  io = x @ Wroot^T + b  (io==d_out, f32)
//     gather: io[i] = [relu]( sum_j w_j * xr[src_j] + io[i] )  in place, ILP-8
// N=100000, E=1600000, D=64

#define D 64
#define SCAN_CHUNK 1024

typedef unsigned int   u32;
typedef unsigned short u16;

__device__ __forceinline__ float bf2f(u16 v) {
    return __uint_as_float(((u32)v) << 16);
}
__device__ __forceinline__ u16 f2bf(float f) {
    u32 u = __float_as_uint(f);
    u32 r = (u + 0x7fffu + ((u >> 16) & 1u)) >> 16;   // round-to-nearest-even
    return (u16)r;
}

// ---------------- CSR build (proven structure) ----------------
__global__ __launch_bounds__(256) void hist_kernel(
    const int* __restrict__ ei, int* __restrict__ deg, int E_)
{
    int e = blockIdx.x * 256 + threadIdx.x;
    if (e >= E_) return;
    atomicAdd(&deg[ei[E_ + e]], 1);
}

__global__ __launch_bounds__(256) void scan1_kernel(
    const int* __restrict__ deg, int* __restrict__ loc, int* __restrict__ partial, int n)
{
    __shared__ int wsum[4];
    int t = threadIdx.x;
    int base = blockIdx.x * SCAN_CHUNK + t * 4;
    int v0 = (base + 0 < n) ? deg[base + 0] : 0;
    int v1 = (base + 1 < n) ? deg[base + 1] : 0;
    int v2 = (base + 2 < n) ? deg[base + 2] : 0;
    int v3 = (base + 3 < n) ? deg[base + 3] : 0;
    int s = v0 + v1 + v2 + v3;
    int lane = t & 63, wave = t >> 6;
    int inc = s;
    for (int off = 1; off < 64; off <<= 1) {
        int u = __shfl_up(inc, off);
        if (lane >= off) inc += u;
    }
    if (lane == 63) wsum[wave] = inc;
    __syncthreads();
    int woff = 0;
    for (int w = 0; w < wave; ++w) woff += wsum[w];
    int ex = woff + inc - s;
    if (base + 0 < n) loc[base + 0] = ex;
    if (base + 1 < n) loc[base + 1] = ex + v0;
    if (base + 2 < n) loc[base + 2] = ex + v0 + v1;
    if (base + 3 < n) loc[base + 3] = ex + v0 + v1 + v2;
    if (t == 255) partial[blockIdx.x] = woff + inc;
}

__global__ __launch_bounds__(1024) void scan2_kernel(int* __restrict__ partial, int nchunk)
{
    __shared__ int sd[1024];
    int t = threadIdx.x;
    if (t < nchunk) sd[t] = partial[t];
    __syncthreads();
    if (t == 0) {
        int run = 0;
        for (int i = 0; i < nchunk; ++i) { int v = sd[i]; sd[i] = run; run += v; }
    }
    __syncthreads();
    if (t < nchunk) partial[t] = sd[t];
}

__global__ __launch_bounds__(256) void scan3_kernel(
    int* __restrict__ rowptr, const int* __restrict__ partial,
    int* __restrict__ cursor, int n, int Etot)
{
    int i = blockIdx.x * 256 + threadIdx.x;
    if (i == 0) rowptr[n] = Etot;
    if (i >= n) return;
    int v = rowptr[i] + partial[i >> 10];
    rowptr[i] = v;
    cursor[i] = v;
}

__global__ __launch_bounds__(256) void fill_kernel(
    const int* __restrict__ ei, const float* __restrict__ ew,
    int* __restrict__ cursor, uint64_t* __restrict__ pairs, int E_)
{
    int e = blockIdx.x * 256 + threadIdx.x;
    if (e >= E_) return;
    int src = ei[e];
    int dst = ei[E_ + e];
    int p = atomicAdd(&cursor[dst], 1);
    // low word = src, high word = weight bits (== float2{src_as_float, w} layout)
    uint64_t packed = (uint64_t)(u32)src | ((uint64_t)__float_as_uint(ew[e]) << 32);
    // system-scope write-through: avoid L2 write-allocate of a line we'll never re-read here
    __hip_atomic_store(&pairs[p], packed, __ATOMIC_RELAXED, __HIP_MEMORY_SCOPE_SYSTEM);
}

// ---------------- pre-transform GEMM (round-6/9 proven; bf16 xr store) ----------------
// xr[i] = xin[i] @ Wrel^T (bf16);  io[i] = xin[i] @ Wroot^T + b (f32).
// xin MAY ALIAS io (layer 2) — each row read before same-row write, same wave.
#define GW 8   // waves/block (512 threads)
#define GR 4   // rows/wave
__global__ __launch_bounds__(512) void gemm_kernel(
    const float* xin,
    const float* __restrict__ Wrel, const float* __restrict__ brel,
    const float* __restrict__ Wroot,
    u16* __restrict__ xr, float* io, int Nn)
{
    __shared__ float WrelT[D][D + 1];   // WrelT[k][d] = Wrel[d*64+k]; pad kills conflicts
    __shared__ float WrootT[D][D + 1];
    __shared__ float bias[D];
    __shared__ float rowX[GW][GR][D];

    int tid = threadIdx.x;
    for (int i = tid; i < D * D; i += 512) {
        int d = i >> 6, k = i & 63;
        WrelT [k][d] = Wrel [i];
        WrootT[k][d] = Wroot[i];
    }
    if (tid < D) bias[tid] = brel[tid];
    __syncthreads();

    int wave = tid >> 6, lane = tid & 63;

    int base = (blockIdx.x * GW + wave) * GR;
    if (base >= Nn) return;             // wave-uniform, after barrier
    int nr = min(GR, Nn - base);

    for (int r = 0; r < nr; ++r)
        rowX[wave][r][lane] = xin[(size_t)(base + r) * D + lane];
    // same-wave LDS write->read (proven rounds 2/5/6/9)

    float aR[GR] = {0.f, 0.f, 0.f, 0.f};
    float aC[GR] = {0.f, 0.f, 0.f, 0.f};
#pragma unroll
    for (int k4 = 0; k4 < 16; ++k4) {
        float4 xv[GR];
#pragma unroll
        for (int r = 0; r < GR; ++r)
            xv[r] = *reinterpret_cast<const float4*>(&rowX[wave][r][k4 * 4]); // broadcast b128
#pragma unroll
        for (int kk = 0; kk < 4; ++kk) {
            float wr = WrelT [k4 * 4 + kk][lane];
            float wc = WrootT[k4 * 4 + kk][lane];
#pragma unroll
            for (int r = 0; r < GR; ++r) {
                float xk = (kk == 0) ? xv[r].x : (kk == 1) ? xv[r].y
                         : (kk == 2) ? xv[r].z : xv[r].w;
                aR[r] = fmaf(xk, wr, aR[r]);
                aC[r] = fmaf(xk, wc, aC[r]);
            }
        }
    }
    for (int r = 0; r < nr; ++r) {
        size_t o = (size_t)(base + r) * D + lane;
        xr[o] = f2bf(aR[r]);            // bf16 store (round-8-proven numerics)
        io[o] = aC[r] + bias[lane];
    }
}

// ---------------- gather: ILP-8, bf16 rows, zero-weight padded ----------------
#define AW 8
template <bool RELU>
__global__ __launch_bounds__(512) void gather_kernel(
    const u16* __restrict__ xr, const uint64_t* __restrict__ pairs,
    const int* __restrict__ rowptr, float* __restrict__ io, int Nn)
{
    int tid  = threadIdx.x;
    int wave = tid >> 6, lane = tid & 63;
    int i = blockIdx.x * AW + wave;
    if (i >= Nn) return;                       // wave-uniform

    int beg = rowptr[i], end = rowptr[i + 1];
    float acc = 0.f;
    for (int b = beg; b < end; b += 64) {
        int cnt = min(64, end - b);
        // lanes >= cnt carry (src=0, w=0): padded edges read row 0, add 0
        uint64_t pv = (lane < cnt) ? __builtin_nontemporal_load(&pairs[b + lane])
                                   : (uint64_t)0;
        int   ps = (int)(u32)pv;
        float wv = __uint_as_float((u32)(pv >> 32));
        for (int j = 0; j < cnt; j += 8) {     // 8 independent gathers in flight
            int   s0 = __shfl(ps, j + 0), s1 = __shfl(ps, j + 1);
            int   s2 = __shfl(ps, j + 2), s3 = __shfl(ps, j + 3);
            int   s4 = __shfl(ps, j + 4), s5 = __shfl(ps, j + 5);
            int   s6 = __shfl(ps, j + 6), s7 = __shfl(ps, j + 7);
            float w0 = __shfl(wv, j + 0), w1 = __shfl(wv, j + 1);
            float w2 = __shfl(wv, j + 2), w3 = __shfl(wv, j + 3);
            float w4 = __shfl(wv, j + 4), w5 = __shfl(wv, j + 5);
            float w6 = __shfl(wv, j + 6), w7 = __shfl(wv, j + 7);
            float v0 = bf2f(xr[(size_t)s0 * D + lane]);
            float v1 = bf2f(xr[(size_t)s1 * D + lane]);
            float v2 = bf2f(xr[(size_t)s2 * D + lane]);
            float v3 = bf2f(xr[(size_t)s3 * D + lane]);
            float v4 = bf2f(xr[(size_t)s4 * D + lane]);
            float v5 = bf2f(xr[(size_t)s5 * D + lane]);
            float v6 = bf2f(xr[(size_t)s6 * D + lane]);
            float v7 = bf2f(xr[(size_t)s7 * D + lane]);
            acc = fmaf(v0, w0, acc); acc = fmaf(v1, w1, acc);
            acc = fmaf(v2, w2, acc); acc = fmaf(v3, w3, acc);
            acc = fmaf(v4, w4, acc); acc = fmaf(v5, w5, acc);
            acc = fmaf(v6, w6, acc); acc = fmaf(v7, w7, acc);
        }
    }
    size_t o = (size_t)i * D + lane;
    float v = acc + io[o];
    io[o] = RELU ? fmaxf(v, 0.f) : v;
}

extern "C" void kernel_launch(void* const* d_in, const int* in_sizes, int n_in,
                              void* d_out, int out_size, void* d_ws, size_t ws_size,
                              hipStream_t stream)
{
    const float* x      = (const float*)d_in[0];
    const int*   ei     = (const int*)  d_in[1];
    const float* ew     = (const float*)d_in[2];
    const float* Wrel1  = (const float*)d_in[3];
    const float* brel1  = (const float*)d_in[4];
    const float* Wroot1 = (const float*)d_in[5];
    const float* Wrel2  = (const float*)d_in[6];
    const float* brel2  = (const float*)d_in[7];
    const float* Wroot2 = (const float*)d_in[8];
    float* out = (float*)d_out;

    const int E_ = in_sizes[2];          // 1600000
    const int Nn = in_sizes[0] / D;      // 100000

    // workspace layout — ~26.4 MB total (under proven 39.2 MB footprint)
    char* w = (char*)d_ws;
    size_t off = 0;
    u16*  xr     = (u16*)(w + off); off += (size_t)Nn * D * sizeof(u16);   // 12.8 MB
    int*  rowptr = (int*)(w + off); off += (size_t)(Nn + 1) * sizeof(int);
    int*  cursor = (int*)(w + off); off += (size_t)Nn * sizeof(int);
    int*  partial= (int*)(w + off); off += 1024 * sizeof(int);
    off = (off + 15) & ~(size_t)15;
    uint64_t* pairs = (uint64_t*)(w + off);                                // 12.8 MB

    const int nchunk  = (Nn + SCAN_CHUNK - 1) / SCAN_CHUNK;
    const int eBlocks = (E_ + 255) / 256;
    const int gemmBlocks   = (Nn + GW * GR - 1) / (GW * GR);
    const int gatherBlocks = (Nn + AW - 1) / AW;

    // ---- CSR build (reused by both layers) ----
    (void)hipMemsetAsync(cursor, 0, (size_t)Nn * sizeof(int), stream);
    hist_kernel<<<eBlocks, 256, 0, stream>>>(ei, cursor, E_);
    scan1_kernel<<<nchunk, 256, 0, stream>>>(cursor, rowptr, partial, Nn);
    scan2_kernel<<<1, 1024, 0, stream>>>(partial, nchunk);
    scan3_kernel<<<(Nn + 255) / 256, 256, 0, stream>>>(rowptr, partial, cursor, Nn, E_);
    fill_kernel<<<eBlocks, 256, 0, stream>>>(ei, ew, cursor, pairs, E_);

    // ---- layer 1: out = x@Wroot1^T+b1;  out = relu(gather(xr1) + out) ----
    gemm_kernel<<<gemmBlocks, 512, 0, stream>>>(x, Wrel1, brel1, Wroot1, xr, out, Nn);
    gather_kernel<true><<<gatherBlocks, 512, 0, stream>>>(xr, pairs, rowptr, out, Nn);

    // ---- layer 2: xr2 = h@Wrel2^T; out = h@Wroot2^T+b2 (in place);  out += gather(xr2) ----
    gemm_kernel<<<gemmBlocks, 512, 0, stream>>>(out, Wrel2, brel2, Wroot2, xr, out, Nn);
    gather_kernel<false><<<gatherBlocks, 512, 0, stream>>>(xr, pairs, rowptr, out, Nn);
}